// Round 13
// baseline (312.656 us; speedup 1.0000x reference)
//
#include <hip/hip_runtime.h>
#include <hip/hip_bf16.h>

typedef unsigned short u16;
typedef unsigned int   u32;
typedef __bf16 bf16x8 __attribute__((ext_vector_type(8)));
typedef float  f32x4  __attribute__((ext_vector_type(4)));
typedef u32    u32x4  __attribute__((ext_vector_type(4)));

#define TRI_TOTAL 131328  // sum_{n=0}^{511} (n+1)

__device__ __forceinline__ float b2f(u16 u) {
    return __builtin_bit_cast(float, ((u32)u) << 16);
}
__device__ __forceinline__ u16 f2b(float f) {  // RNE f32->bf16
    u32 u = __builtin_bit_cast(u32, f);
    return (u16)((u + 0x7fffu + ((u >> 16) & 1u)) >> 16);
}

// ---------------- LayerNorm -> xn (bf16) ----------------
__global__ void __launch_bounds__(256) ln_kernel(const float* __restrict__ x,
                                                 const float* __restrict__ g,
                                                 const float* __restrict__ b,
                                                 u16* __restrict__ xn) {
    int n = blockIdx.x, t = threadIdx.x;
    float v = x[n * 256 + t];
    __shared__ float red[4];
    float s = v;
    #pragma unroll
    for (int o = 32; o >= 1; o >>= 1) s += __shfl_xor(s, o);
    if ((t & 63) == 0) red[t >> 6] = s;
    __syncthreads();
    float mu = (red[0] + red[1] + red[2] + red[3]) * (1.0f / 256.0f);
    float d = v - mu;
    __syncthreads();
    float s2 = d * d;
    #pragma unroll
    for (int o = 32; o >= 1; o >>= 1) s2 += __shfl_xor(s2, o);
    if ((t & 63) == 0) red[t >> 6] = s2;
    __syncthreads();
    float var = (red[0] + red[1] + red[2] + red[3]) * (1.0f / 256.0f);
    float y = d * rsqrtf(var + 1e-5f) * g[t] + b[t];
    xn[n * 256 + t] = f2b(y);
}

// ---------------- Per-relative-index projections (v13) ----------------
// Q/V: qd[r,m] = xn[m] @ W[r], needed m in [0, 512-r).  Stored at tri(r+m)+m.
// K:   kd[r,pos] = xn[pos] @ Wk[r], needed pos in [511-r, 512).
//      Stored at tri(pos) + (pos-(511-r)).
// v13: W fragments live in 16 NAMED bf16x8 registers per wave, loaded straight
// from global once per block (they're loop-invariant!). LDS holds only the A
// tile (32 KB). m-loop per k-step: 2 ds_read + 4 MFMA, zero B traffic. The
// whole Wl staging/swizzle machinery is deleted.
__global__ void __launch_bounds__(256, 2) proj_kernel(
        const u16* __restrict__ xn,
        const float* __restrict__ Wq, const float* __restrict__ Wk,
        const float* __restrict__ Wv,
        u16* __restrict__ Qa, u16* __restrict__ Ka, u16* __restrict__ Va) {
    __shared__ u16 Al[64 * 256];   // [row][k] bf16, (row&7)<<4-swizzled

    int bid = blockIdx.x;
    int which = bid >> 11;          // 0=Q,1=K,2=V (2048 blocks each)
    int rr = bid & 2047;
    int r  = (which == 1) ? (511 - (rr >> 2)) : (rr >> 2);  // heavy first
    int cs = rr & 3;
    const float* W = (which == 0) ? Wq : ((which == 1) ? Wk : Wv);
    u16* Out       = (which == 0) ? Qa : ((which == 1) ? Ka : Va);
    int rows  = (which == 1) ? (r + 1) : (512 - r);
    int pbase = (which == 1) ? (511 - r) : 0;   // xn position = pbase + ml
    int nbase = (which == 1) ? (511 - r) : r;   // attn row n = nbase + ml

    int t = threadIdx.x;
    int c0 = cs * 64;
    int wv  = t >> 6;               // 0..3
    int rg  = wv >> 1;              // row-group: rows [rg*32, rg*32+32)
    int cg  = wv & 1;               // col-group: cols [cg*32, cg*32+32)
    int L   = t & 63;
    int l15 = L & 15, l4 = L >> 4;

    // ---- A staging: thread covers rows {srow+8i}, one 16B slot ----
    int srow   = t >> 5;            // 0..7
    int slot16 = (t & 31) * 16;
    char* adp = (char*)Al + srow * 512 + (slot16 ^ (srow << 4));
    u32x4 ar0, ar1, ar2, ar3, ar4, ar5, ar6, ar7;

#define A_LOAD(M0) do {                                                       \
    int gg;                                                                   \
    gg = pbase + (M0) +  0 + srow; if (gg > 511) gg = 511;                    \
    ar0 = *(const u32x4*)((const char*)xn + (size_t)gg * 512 + slot16);       \
    gg = pbase + (M0) +  8 + srow; if (gg > 511) gg = 511;                    \
    ar1 = *(const u32x4*)((const char*)xn + (size_t)gg * 512 + slot16);       \
    gg = pbase + (M0) + 16 + srow; if (gg > 511) gg = 511;                    \
    ar2 = *(const u32x4*)((const char*)xn + (size_t)gg * 512 + slot16);       \
    gg = pbase + (M0) + 24 + srow; if (gg > 511) gg = 511;                    \
    ar3 = *(const u32x4*)((const char*)xn + (size_t)gg * 512 + slot16);       \
    gg = pbase + (M0) + 32 + srow; if (gg > 511) gg = 511;                    \
    ar4 = *(const u32x4*)((const char*)xn + (size_t)gg * 512 + slot16);       \
    gg = pbase + (M0) + 40 + srow; if (gg > 511) gg = 511;                    \
    ar5 = *(const u32x4*)((const char*)xn + (size_t)gg * 512 + slot16);       \
    gg = pbase + (M0) + 48 + srow; if (gg > 511) gg = 511;                    \
    ar6 = *(const u32x4*)((const char*)xn + (size_t)gg * 512 + slot16);       \
    gg = pbase + (M0) + 56 + srow; if (gg > 511) gg = 511;                    \
    ar7 = *(const u32x4*)((const char*)xn + (size_t)gg * 512 + slot16);       \
} while (0)

#define A_WRITE() do {                                                        \
    *(u32x4*)(adp + 0 * 4096) = ar0;                                          \
    *(u32x4*)(adp + 1 * 4096) = ar1;                                          \
    *(u32x4*)(adp + 2 * 4096) = ar2;                                          \
    *(u32x4*)(adp + 3 * 4096) = ar3;                                          \
    *(u32x4*)(adp + 4 * 4096) = ar4;                                          \
    *(u32x4*)(adp + 5 * 4096) = ar5;                                          \
    *(u32x4*)(adp + 6 * 4096) = ar6;                                          \
    *(u32x4*)(adp + 7 * 4096) = ar7;                                          \
} while (0)

    A_LOAD(0);                      // first A-tile: oldest loads in queue

    // ---- B fragments: 16 named bf16x8, loaded once from global W ----
    // k element = ks*32 + l4*8 + j  (stride 256 floats); col = c0+cg*32+hf*16+l15
    const float* wbase = W + ((size_t)r << 16) + c0 + cg * 32 + l15;
    bf16x8 b00, b01, b02, b03, b04, b05, b06, b07;
    bf16x8 b10, b11, b12, b13, b14, b15, b16, b17;
#define BLOAD(HF, KSI, DST) {                                                 \
    const float* wp = wbase + (size_t)((KSI) * 32 + l4 * 8) * 256 + (HF) * 16;\
    u32x4 pk;                                                                 \
    pk[0] = (u32)f2b(wp[0])    | ((u32)f2b(wp[256])  << 16);                  \
    pk[1] = (u32)f2b(wp[512])  | ((u32)f2b(wp[768])  << 16);                  \
    pk[2] = (u32)f2b(wp[1024]) | ((u32)f2b(wp[1280]) << 16);                  \
    pk[3] = (u32)f2b(wp[1536]) | ((u32)f2b(wp[1792]) << 16);                  \
    DST = __builtin_bit_cast(bf16x8, pk); }
    BLOAD(0, 0, b00) BLOAD(0, 1, b01) BLOAD(0, 2, b02) BLOAD(0, 3, b03)
    BLOAD(0, 4, b04) BLOAD(0, 5, b05) BLOAD(0, 6, b06) BLOAD(0, 7, b07)
    BLOAD(1, 0, b10) BLOAD(1, 1, b11) BLOAD(1, 2, b12) BLOAD(1, 3, b13)
    BLOAD(1, 4, b14) BLOAD(1, 5, b15) BLOAD(1, 6, b16) BLOAD(1, 7, b17)
#undef BLOAD

    const char* a_base = (const char*)Al + (rg * 32 + l15) * 512;
    int am = (l15 & 7) << 4;

    for (int m0 = 0; m0 < rows; m0 += 64) {
        A_WRITE();
        __syncthreads();                // Al ready
        if (m0 + 64 < rows) A_LOAD(m0 + 64);   // T14: issue early

        f32x4 acc00 = {}, acc01 = {}, acc10 = {}, acc11 = {};
#define KS(ks) {                                                              \
        int kb = (ks) * 64 + l4 * 16;                                         \
        bf16x8 a0 = *(const bf16x8*)(a_base + (kb ^ am));                     \
        bf16x8 a1 = *(const bf16x8*)(a_base + 16 * 512 + (kb ^ am));          \
        acc00 = __builtin_amdgcn_mfma_f32_16x16x32_bf16(a0, b0##ks, acc00, 0, 0, 0); \
        acc01 = __builtin_amdgcn_mfma_f32_16x16x32_bf16(a0, b1##ks, acc01, 0, 0, 0); \
        acc10 = __builtin_amdgcn_mfma_f32_16x16x32_bf16(a1, b0##ks, acc10, 0, 0, 0); \
        acc11 = __builtin_amdgcn_mfma_f32_16x16x32_bf16(a1, b1##ks, acc11, 0, 0, 0); \
    }
        KS(0) KS(1) KS(2) KS(3) KS(4) KS(5) KS(6) KS(7)
#undef KS

        // store to packed attention layout
        #pragma unroll
        for (int rf = 0; rf < 2; ++rf) {
            #pragma unroll
            for (int j = 0; j < 4; ++j) {
                int ml = m0 + rg * 32 + rf * 16 + l4 * 4 + j;
                if (ml < rows) {
                    int nout = nbase + ml;
                    size_t prow = (size_t)(nout * (nout + 1) / 2) + (size_t)ml;
                    u16* op = Out + prow * 256 + c0 + cg * 32 + l15;
                    f32x4 va = rf ? acc10 : acc00;
                    f32x4 vb = rf ? acc11 : acc01;
                    op[0]  = f2b(va[j]);
                    op[16] = f2b(vb[j]);
                }
            }
        }
        __syncthreads();                // Al fully consumed
    }
#undef A_WRITE
#undef A_LOAD
}

// ---------------- per-row attention ----------------
// Block = one query row n. Band rows tri(n)..tri(n)+n hold per-pair q,k,v.
__global__ void __launch_bounds__(256) attn_kernel(const u16* __restrict__ Qa,
                                                   const u16* __restrict__ Ka,
                                                   const u16* __restrict__ Va,
                                                   float* __restrict__ ao) {
    int n = blockIdx.x, t = threadIdx.x;
    __shared__ float pbuf[512 * 9];   // [m][h] padded pitch 9
    __shared__ float linv[8];
    int band = n + 1;
    size_t rb = (size_t)(n * (n + 1) / 2);

    // scores: thread = (m-inner, h)
    int h = t & 7, mi = t >> 3;
    for (int m0 = 0; m0 < band; m0 += 32) {
        int m = m0 + mi;
        float d = -1e30f;
        if (m < band) {
            const char* qp = (const char*)Qa + (rb + m) * 512 + h * 64;
            const char* kp = (const char*)Ka + (rb + m) * 512 + h * 64;
            float acc = 0.f;
            #pragma unroll
            for (int cch = 0; cch < 4; ++cch) {
                u32x4 qv = *reinterpret_cast<const u32x4*>(qp + cch * 16);
                u32x4 kv = *reinterpret_cast<const u32x4*>(kp + cch * 16);
                #pragma unroll
                for (int i = 0; i < 4; ++i) {
                    float ql = __builtin_bit_cast(float, qv[i] << 16);
                    float qh = __builtin_bit_cast(float, qv[i] & 0xffff0000u);
                    float kl = __builtin_bit_cast(float, kv[i] << 16);
                    float kh = __builtin_bit_cast(float, kv[i] & 0xffff0000u);
                    acc += ql * kl + qh * kh;
                }
            }
            d = acc * 0.17677669529663687f;  // 1/sqrt(32)
        }
        pbuf[m * 9 + h] = d;
    }
    __syncthreads();

    // softmax per head: wave wv handles heads wv and wv+4
    int wv = t >> 6, L = t & 63;
    for (int s = 0; s < 2; ++s) {
        int hh = wv + s * 4;
        float mx = -1e30f;
        for (int m = L; m < band; m += 64) mx = fmaxf(mx, pbuf[m * 9 + hh]);
        #pragma unroll
        for (int o = 32; o >= 1; o >>= 1) mx = fmaxf(mx, __shfl_xor(mx, o));
        float sum = 0.f;
        for (int m = L; m < band; m += 64) {
            float p = __expf(pbuf[m * 9 + hh] - mx);
            pbuf[m * 9 + hh] = p;
            sum += p;
        }
        #pragma unroll
        for (int o = 32; o >= 1; o >>= 1) sum += __shfl_xor(sum, o);
        if (L == 0) linv[hh] = 1.0f / sum;
    }
    __syncthreads();

    // PV: thread = output channel t = h*32+e
    int h2 = t >> 5;
    const char* vp = (const char*)Va + rb * 512 + (size_t)t * 2;
    const float* pb = pbuf + h2;
    float a0 = 0, a1 = 0, a2 = 0, a3 = 0;
    int m = 0;
    for (; m + 4 <= band; m += 4) {
        a0 += pb[(m + 0) * 9] * b2f(*(const u16*)(vp + (size_t)(m + 0) * 512));
        a1 += pb[(m + 1) * 9] * b2f(*(const u16*)(vp + (size_t)(m + 1) * 512));
        a2 += pb[(m + 2) * 9] * b2f(*(const u16*)(vp + (size_t)(m + 2) * 512));
        a3 += pb[(m + 3) * 9] * b2f(*(const u16*)(vp + (size_t)(m + 3) * 512));
    }
    for (; m < band; ++m)
        a0 += pb[m * 9] * b2f(*(const u16*)(vp + (size_t)m * 512));
    ao[n * 256 + t] = ((a0 + a1) + (a2 + a3)) * linv[h2];
}

// ---------------- output projection ----------------
__global__ void __launch_bounds__(256) outproj_kernel(const float* __restrict__ ao,
                                                      const float* __restrict__ Wo,
                                                      const float* __restrict__ bo,
                                                      float* __restrict__ out) {
    int n = blockIdx.x, e = threadIdx.x;
    const float* a = ao + n * 256;
    float c0 = bo[e], c1 = 0, c2 = 0, c3 = 0;
    for (int c = 0; c < 256; c += 4) {
        c0 += a[c + 0] * Wo[(c + 0) * 256 + e];
        c1 += a[c + 1] * Wo[(c + 1) * 256 + e];
        c2 += a[c + 2] * Wo[(c + 2) * 256 + e];
        c3 += a[c + 3] * Wo[(c + 3) * 256 + e];
    }
    out[n * 256 + e] = (c0 + c1) + (c2 + c3);
}

extern "C" void kernel_launch(void* const* d_in, const int* in_sizes, int n_in,
                              void* d_out, int out_size, void* d_ws, size_t ws_size,
                              hipStream_t stream) {
    const float* x     = (const float*)d_in[0];
    const float* Wq    = (const float*)d_in[1];
    const float* Wk    = (const float*)d_in[2];
    const float* Wv    = (const float*)d_in[3];
    const float* gamma = (const float*)d_in[4];
    const float* beta  = (const float*)d_in[5];
    const float* Wo    = (const float*)d_in[6];
    const float* bo    = (const float*)d_in[7];
    float* out = (float*)d_out;

    char* ws = (char*)d_ws;
    u16* xn = (u16*)ws;
    size_t off = (size_t)512 * 256 * 2;
    u16* Qa = (u16*)(ws + off); off += (size_t)TRI_TOTAL * 256 * 2;
    u16* Ka = (u16*)(ws + off); off += (size_t)TRI_TOTAL * 256 * 2;
    u16* Va = (u16*)(ws + off); off += (size_t)TRI_TOTAL * 256 * 2;
    float* ao = (float*)(ws + off);

    ln_kernel<<<512, 256, 0, stream>>>(x, gamma, beta, xn);
    proj_kernel<<<6144, 256, 0, stream>>>(xn, Wq, Wk, Wv, Qa, Ka, Va);
    attn_kernel<<<512, 256, 0, stream>>>(Qa, Ka, Va, ao);
    outproj_kernel<<<512, 256, 0, stream>>>(ao, Wo, bo, out);
}

// Round 14
// 268.035 us; speedup vs baseline: 1.1665x; 1.1665x over previous
//
#include <hip/hip_runtime.h>
#include <hip/hip_bf16.h>

typedef unsigned short u16;
typedef unsigned int   u32;
typedef __bf16 bf16x8 __attribute__((ext_vector_type(8)));
typedef float  f32x4  __attribute__((ext_vector_type(4)));
typedef u32    u32x4  __attribute__((ext_vector_type(4)));
typedef u32    u32x2  __attribute__((ext_vector_type(2)));

#define TRI_TOTAL 131328  // sum_{n=0}^{511} (n+1)

__device__ __forceinline__ float b2f(u16 u) {
    return __builtin_bit_cast(float, ((u32)u) << 16);
}
__device__ __forceinline__ u16 f2b(float f) {  // RNE f32->bf16
    u32 u = __builtin_bit_cast(u32, f);
    return (u16)((u + 0x7fffu + ((u >> 16) & 1u)) >> 16);
}
// Wl swizzle: <=2-way (free) for k-fast reads and col-fast writes
__device__ __forceinline__ int pcol(int col) {
    return (((col & 7) ^ ((col >> 3) & 7)) << 4);
}
// async global->LDS, 16B per lane, wave-uniform LDS base
__device__ __forceinline__ void gload_lds16(const void* g, void* l) {
    __builtin_amdgcn_global_load_lds(
        (const __attribute__((address_space(1))) void*)g,
        (__attribute__((address_space(3))) void*)l, 16, 0, 0);
}

// ---------------- LayerNorm -> xn (bf16) ----------------
__global__ void __launch_bounds__(256) ln_kernel(const float* __restrict__ x,
                                                 const float* __restrict__ g,
                                                 const float* __restrict__ b,
                                                 u16* __restrict__ xn) {
    int n = blockIdx.x, t = threadIdx.x;
    float v = x[n * 256 + t];
    __shared__ float red[4];
    float s = v;
    #pragma unroll
    for (int o = 32; o >= 1; o >>= 1) s += __shfl_xor(s, o);
    if ((t & 63) == 0) red[t >> 6] = s;
    __syncthreads();
    float mu = (red[0] + red[1] + red[2] + red[3]) * (1.0f / 256.0f);
    float d = v - mu;
    __syncthreads();
    float s2 = d * d;
    #pragma unroll
    for (int o = 32; o >= 1; o >>= 1) s2 += __shfl_xor(s2, o);
    if ((t & 63) == 0) red[t >> 6] = s2;
    __syncthreads();
    float var = (red[0] + red[1] + red[2] + red[3]) * (1.0f / 256.0f);
    float y = d * rsqrtf(var + 1e-5f) * g[t] + b[t];
    xn[n * 256 + t] = f2b(y);
}

// ---------------- Per-relative-index projections (v14) ----------------
// Q/V: qd[r,m] = xn[m] @ W[r], needed m in [0, 512-r).  Stored at tri(r+m)+m.
// K:   kd[r,pos] = xn[pos] @ Wk[r], needed pos in [511-r, 512).
//      Stored at tri(pos) + (pos-(511-r)).
// v14: B-frags in 16 named regs extracted via ds_read from the LDS-staged Wl
// (coalesced dwordx4 HBM stream). A-tiles staged by ASYNC global_load_lds
// (zero VGPR, can't be compiler-sunk), double-buffered: Wl's 32 KB becomes
// the second A buffer after extraction. One barrier/tile; DMA of tile i+1
// hides under tile i's compute. Per k-step: 2 ds_read -> 4 MFMA (512B/MFMA).
// LDS source swizzle: linear dest + inverse-swizzled global src (rule #21).
__global__ void __launch_bounds__(256) proj_kernel(
        const u16* __restrict__ xn,
        const float* __restrict__ Wq, const float* __restrict__ Wk,
        const float* __restrict__ Wv,
        u16* __restrict__ Qa, u16* __restrict__ Ka, u16* __restrict__ Va) {
    __shared__ char lds[65536];
    char* buf0 = lds;            // Wl first, then odd tiles
    char* buf1 = lds + 32768;    // even tiles

    int bid = blockIdx.x;
    int which = bid >> 11;          // 0=Q,1=K,2=V (2048 blocks each)
    int rr = bid & 2047;
    int r  = (which == 1) ? (511 - (rr >> 2)) : (rr >> 2);  // heavy first
    int cs = rr & 3;
    const float* W = (which == 0) ? Wq : ((which == 1) ? Wk : Wv);
    u16* Out       = (which == 0) ? Qa : ((which == 1) ? Ka : Va);
    int rows  = (which == 1) ? (r + 1) : (512 - r);
    int pbase = (which == 1) ? (511 - r) : 0;   // xn position = pbase + ml
    int nbase = (which == 1) ? (511 - r) : r;   // attn row n = nbase + ml

    int t = threadIdx.x;
    int c0 = cs * 64;
    int wv  = t >> 6;               // 0..3
    int rg  = wv >> 1;              // row-group: rows [rg*32, rg*32+32)
    int cg  = wv & 1;               // col-group: cols [cg*32, cg*32+32)
    int L   = t & 63;
    int l15 = L & 15, l4 = L >> 4;

    // ---- async A-tile DMA: wave wv covers tile rows [wv*16, wv*16+16) ----
    // LDS linear; global source pre-swizzled: LDS[row][s] = xn[grow][s^(row&7)]
#define DMA_TILE(DST, M0) do {                                                \
    _Pragma("unroll")                                                         \
    for (int j = 0; j < 8; ++j) {                                             \
        int lrow = wv * 16 + 2 * j + (L >> 5);                                \
        int grow = pbase + (M0) + lrow; if (grow > 511) grow = 511;           \
        const char* gp = (const char*)xn + (size_t)grow * 512                 \
                         + (((L & 31) ^ (lrow & 7)) << 4);                    \
        char* lp = (DST) + (wv * 16 + 2 * j) * 512;                           \
        gload_lds16(gp, lp);                                                  \
    }                                                                         \
} while (0)

    DMA_TILE(buf1, 0);              // tile 0 flies under the W stage

    // ---- Wl stage into buf0: coalesced dwordx4 loads, pcol b64 writes ----
    {
        int c4 = (t & 15) * 4;      // 4 consecutive cols
        int kq = t >> 4;            // 0..15 -> k-quad base kq*4 (+64/IT)
        const float* wp = W + ((size_t)r << 16) + c0 + c4 + (size_t)(kq * 4) * 256;
        f32x4 w00 = *(const f32x4*)(wp + 0);
        f32x4 w01 = *(const f32x4*)(wp + 256);
        f32x4 w02 = *(const f32x4*)(wp + 512);
        f32x4 w03 = *(const f32x4*)(wp + 768);
        f32x4 w10 = *(const f32x4*)(wp + 16384 + 0);
        f32x4 w11 = *(const f32x4*)(wp + 16384 + 256);
        f32x4 w12 = *(const f32x4*)(wp + 16384 + 512);
        f32x4 w13 = *(const f32x4*)(wp + 16384 + 768);
        f32x4 w20 = *(const f32x4*)(wp + 32768 + 0);
        f32x4 w21 = *(const f32x4*)(wp + 32768 + 256);
        f32x4 w22 = *(const f32x4*)(wp + 32768 + 512);
        f32x4 w23 = *(const f32x4*)(wp + 32768 + 768);
        f32x4 w30 = *(const f32x4*)(wp + 49152 + 0);
        f32x4 w31 = *(const f32x4*)(wp + 49152 + 256);
        f32x4 w32 = *(const f32x4*)(wp + 49152 + 512);
        f32x4 w33 = *(const f32x4*)(wp + 49152 + 768);
#define WLW(IT, VA, VB, VC, VD) {                                             \
        int kbase2 = (kq * 4 + (IT) * 64) * 2;                                \
        _Pragma("unroll")                                                     \
        for (int i = 0; i < 4; ++i) {                                         \
            int col = c4 + i;                                                 \
            u32 lo = (u32)f2b(VA[i]) | ((u32)f2b(VB[i]) << 16);               \
            u32 hi = (u32)f2b(VC[i]) | ((u32)f2b(VD[i]) << 16);               \
            u32x2 pr; pr[0] = lo; pr[1] = hi;                                 \
            *(u32x2*)(buf0 + col * 512 + (kbase2 ^ pcol(col))) = pr;          \
        }                                                                     \
    }
        WLW(0, w00, w01, w02, w03)
        WLW(1, w10, w11, w12, w13)
        WLW(2, w20, w21, w22, w23)
        WLW(3, w30, w31, w32, w33)
#undef WLW
    }
    __syncthreads();                // Wl ready; tile-0 DMA drained

    // ---- B-frag extraction: 16 named bf16x8 from Wl ----
    bf16x8 b00, b01, b02, b03, b04, b05, b06, b07;
    bf16x8 b10, b11, b12, b13, b14, b15, b16, b17;
#define BEXT(HF, KSI, DST) {                                                  \
    int col = cg * 32 + (HF) * 16 + l15;                                      \
    int kb = (KSI) * 64 + l4 * 16;                                            \
    DST = *(const bf16x8*)(buf0 + col * 512 + (kb ^ pcol(col))); }
    BEXT(0, 0, b00) BEXT(0, 1, b01) BEXT(0, 2, b02) BEXT(0, 3, b03)
    BEXT(0, 4, b04) BEXT(0, 5, b05) BEXT(0, 6, b06) BEXT(0, 7, b07)
    BEXT(1, 0, b10) BEXT(1, 1, b11) BEXT(1, 2, b12) BEXT(1, 3, b13)
    BEXT(1, 4, b14) BEXT(1, 5, b15) BEXT(1, 6, b16) BEXT(1, 7, b17)
#undef BEXT
    __syncthreads();                // all extracts done; buf0 reusable as A

    int am = (l15 & 7) << 4;
    int nt = (rows + 63) >> 6;
    char* cur = buf1;
    char* alt = buf0;

    for (int i = 0; i < nt; ++i) {
        int m0 = i << 6;
        if (i + 1 < nt) DMA_TILE(alt, m0 + 64);   // async, hides under compute

        const char* abase = cur + (rg * 32 + l15) * 512;
        f32x4 acc00 = {}, acc01 = {}, acc10 = {}, acc11 = {};
#define KS(ks) {                                                              \
        int kb = (ks) * 64 + l4 * 16;                                         \
        bf16x8 a0 = *(const bf16x8*)(abase + (kb ^ am));                      \
        bf16x8 a1 = *(const bf16x8*)(abase + 16 * 512 + (kb ^ am));           \
        acc00 = __builtin_amdgcn_mfma_f32_16x16x32_bf16(a0, b0##ks, acc00, 0, 0, 0); \
        acc01 = __builtin_amdgcn_mfma_f32_16x16x32_bf16(a0, b1##ks, acc01, 0, 0, 0); \
        acc10 = __builtin_amdgcn_mfma_f32_16x16x32_bf16(a1, b0##ks, acc10, 0, 0, 0); \
        acc11 = __builtin_amdgcn_mfma_f32_16x16x32_bf16(a1, b1##ks, acc11, 0, 0, 0); \
    }
        KS(0) KS(1) KS(2) KS(3) KS(4) KS(5) KS(6) KS(7)
#undef KS

        // store to packed attention layout
        #pragma unroll
        for (int rf = 0; rf < 2; ++rf) {
            #pragma unroll
            for (int j = 0; j < 4; ++j) {
                int ml = m0 + rg * 32 + rf * 16 + l4 * 4 + j;
                if (ml < rows) {
                    int nout = nbase + ml;
                    size_t prow = (size_t)(nout * (nout + 1) / 2) + (size_t)ml;
                    u16* op = Out + prow * 256 + c0 + cg * 32 + l15;
                    f32x4 va = rf ? acc10 : acc00;
                    f32x4 vb = rf ? acc11 : acc01;
                    op[0]  = f2b(va[j]);
                    op[16] = f2b(vb[j]);
                }
            }
        }
        __syncthreads();            // drains DMA(i+1) + stores; syncs waves
        char* tmp = cur; cur = alt; alt = tmp;
    }
#undef DMA_TILE
}

// ---------------- per-row attention ----------------
// Block = one query row n. Band rows tri(n)..tri(n)+n hold per-pair q,k,v.
__global__ void __launch_bounds__(256) attn_kernel(const u16* __restrict__ Qa,
                                                   const u16* __restrict__ Ka,
                                                   const u16* __restrict__ Va,
                                                   float* __restrict__ ao) {
    int n = blockIdx.x, t = threadIdx.x;
    __shared__ float pbuf[512 * 9];   // [m][h] padded pitch 9
    __shared__ float linv[8];
    int band = n + 1;
    size_t rb = (size_t)(n * (n + 1) / 2);

    // scores: thread = (m-inner, h)
    int h = t & 7, mi = t >> 3;
    for (int m0 = 0; m0 < band; m0 += 32) {
        int m = m0 + mi;
        float d = -1e30f;
        if (m < band) {
            const char* qp = (const char*)Qa + (rb + m) * 512 + h * 64;
            const char* kp = (const char*)Ka + (rb + m) * 512 + h * 64;
            float acc = 0.f;
            #pragma unroll
            for (int cch = 0; cch < 4; ++cch) {
                u32x4 qv = *reinterpret_cast<const u32x4*>(qp + cch * 16);
                u32x4 kv = *reinterpret_cast<const u32x4*>(kp + cch * 16);
                #pragma unroll
                for (int i = 0; i < 4; ++i) {
                    float ql = __builtin_bit_cast(float, qv[i] << 16);
                    float qh = __builtin_bit_cast(float, qv[i] & 0xffff0000u);
                    float kl = __builtin_bit_cast(float, kv[i] << 16);
                    float kh = __builtin_bit_cast(float, kv[i] & 0xffff0000u);
                    acc += ql * kl + qh * kh;
                }
            }
            d = acc * 0.17677669529663687f;  // 1/sqrt(32)
        }
        pbuf[m * 9 + h] = d;
    }
    __syncthreads();

    // softmax per head: wave wv handles heads wv and wv+4
    int wv = t >> 6, L = t & 63;
    for (int s = 0; s < 2; ++s) {
        int hh = wv + s * 4;
        float mx = -1e30f;
        for (int m = L; m < band; m += 64) mx = fmaxf(mx, pbuf[m * 9 + hh]);
        #pragma unroll
        for (int o = 32; o >= 1; o >>= 1) mx = fmaxf(mx, __shfl_xor(mx, o));
        float sum = 0.f;
        for (int m = L; m < band; m += 64) {
            float p = __expf(pbuf[m * 9 + hh] - mx);
            pbuf[m * 9 + hh] = p;
            sum += p;
        }
        #pragma unroll
        for (int o = 32; o >= 1; o >>= 1) sum += __shfl_xor(sum, o);
        if (L == 0) linv[hh] = 1.0f / sum;
    }
    __syncthreads();

    // PV: thread = output channel t = h*32+e
    int h2 = t >> 5;
    const char* vp = (const char*)Va + rb * 512 + (size_t)t * 2;
    const float* pb = pbuf + h2;
    float a0 = 0, a1 = 0, a2 = 0, a3 = 0;
    int m = 0;
    for (; m + 4 <= band; m += 4) {
        a0 += pb[(m + 0) * 9] * b2f(*(const u16*)(vp + (size_t)(m + 0) * 512));
        a1 += pb[(m + 1) * 9] * b2f(*(const u16*)(vp + (size_t)(m + 1) * 512));
        a2 += pb[(m + 2) * 9] * b2f(*(const u16*)(vp + (size_t)(m + 2) * 512));
        a3 += pb[(m + 3) * 9] * b2f(*(const u16*)(vp + (size_t)(m + 3) * 512));
    }
    for (; m < band; ++m)
        a0 += pb[m * 9] * b2f(*(const u16*)(vp + (size_t)m * 512));
    ao[n * 256 + t] = ((a0 + a1) + (a2 + a3)) * linv[h2];
}

// ---------------- output projection ----------------
__global__ void __launch_bounds__(256) outproj_kernel(const float* __restrict__ ao,
                                                      const float* __restrict__ Wo,
                                                      const float* __restrict__ bo,
                                                      float* __restrict__ out) {
    int n = blockIdx.x, e = threadIdx.x;
    const float* a = ao + n * 256;
    float c0 = bo[e], c1 = 0, c2 = 0, c3 = 0;
    for (int c = 0; c < 256; c += 4) {
        c0 += a[c + 0] * Wo[(c + 0) * 256 + e];
        c1 += a[c + 1] * Wo[(c + 1) * 256 + e];
        c2 += a[c + 2] * Wo[(c + 2) * 256 + e];
        c3 += a[c + 3] * Wo[(c + 3) * 256 + e];
    }
    out[n * 256 + e] = (c0 + c1) + (c2 + c3);
}

extern "C" void kernel_launch(void* const* d_in, const int* in_sizes, int n_in,
                              void* d_out, int out_size, void* d_ws, size_t ws_size,
                              hipStream_t stream) {
    const float* x     = (const float*)d_in[0];
    const float* Wq    = (const float*)d_in[1];
    const float* Wk    = (const float*)d_in[2];
    const float* Wv    = (const float*)d_in[3];
    const float* gamma = (const float*)d_in[4];
    const float* beta  = (const float*)d_in[5];
    const float* Wo    = (const float*)d_in[6];
    const float* bo    = (const float*)d_in[7];
    float* out = (float*)d_out;

    char* ws = (char*)d_ws;
    u16* xn = (u16*)ws;
    size_t off = (size_t)512 * 256 * 2;
    u16* Qa = (u16*)(ws + off); off += (size_t)TRI_TOTAL * 256 * 2;
    u16* Ka = (u16*)(ws + off); off += (size_t)TRI_TOTAL * 256 * 2;
    u16* Va = (u16*)(ws + off); off += (size_t)TRI_TOTAL * 256 * 2;
    float* ao = (float*)(ws + off);

    ln_kernel<<<512, 256, 0, stream>>>(x, gamma, beta, xn);
    proj_kernel<<<6144, 256, 0, stream>>>(xn, Wq, Wk, Wv, Qa, Ka, Va);
    attn_kernel<<<512, 256, 0, stream>>>(Qa, Ka, Va, ao);
    outproj_kernel<<<512, 256, 0, stream>>>(ao, Wo, bo, out);
}

// Round 15
// 263.253 us; speedup vs baseline: 1.1877x; 1.0182x over previous
//
#include <hip/hip_runtime.h>
#include <hip/hip_bf16.h>

typedef unsigned short u16;
typedef unsigned int   u32;
typedef __bf16 bf16x8 __attribute__((ext_vector_type(8)));
typedef float  f32x4  __attribute__((ext_vector_type(4)));
typedef u32    u32x4  __attribute__((ext_vector_type(4)));
typedef u32    u32x2  __attribute__((ext_vector_type(2)));

#define TRI_TOTAL 131328  // sum_{n=0}^{511} (n+1)

__device__ __forceinline__ float b2f(u16 u) {
    return __builtin_bit_cast(float, ((u32)u) << 16);
}
// RNE f32->bf16 via compiler intrinsic (emits v_cvt_pk_bf16_f32 for pairs)
__device__ __forceinline__ u16 f2b(float f) {
    return __builtin_bit_cast(u16, __float2bfloat16(f));
}
// Wl swizzle: <=2-way (free) for k-fast reads and col-fast writes
__device__ __forceinline__ int pcol(int col) {
    return (((col & 7) ^ ((col >> 3) & 7)) << 4);
}
// async global->LDS, 16B per lane, wave-uniform LDS base
__device__ __forceinline__ void gload_lds16(const void* g, void* l) {
    __builtin_amdgcn_global_load_lds(
        (const __attribute__((address_space(1))) void*)g,
        (__attribute__((address_space(3))) void*)l, 16, 0, 0);
}

// ---------------- LayerNorm -> xn (bf16) ----------------
__global__ void __launch_bounds__(256) ln_kernel(const float* __restrict__ x,
                                                 const float* __restrict__ g,
                                                 const float* __restrict__ b,
                                                 u16* __restrict__ xn) {
    int n = blockIdx.x, t = threadIdx.x;
    float v = x[n * 256 + t];
    __shared__ float red[4];
    float s = v;
    #pragma unroll
    for (int o = 32; o >= 1; o >>= 1) s += __shfl_xor(s, o);
    if ((t & 63) == 0) red[t >> 6] = s;
    __syncthreads();
    float mu = (red[0] + red[1] + red[2] + red[3]) * (1.0f / 256.0f);
    float d = v - mu;
    __syncthreads();
    float s2 = d * d;
    #pragma unroll
    for (int o = 32; o >= 1; o >>= 1) s2 += __shfl_xor(s2, o);
    if ((t & 63) == 0) red[t >> 6] = s2;
    __syncthreads();
    float var = (red[0] + red[1] + red[2] + red[3]) * (1.0f / 256.0f);
    float y = d * rsqrtf(var + 1e-5f) * g[t] + b[t];
    xn[n * 256 + t] = f2b(y);
}

// ---------------- Per-relative-index projections (v15) ----------------
// Q/V: qd[r,m] = xn[m] @ W[r], needed m in [0, 512-r).  Stored at tri(r+m)+m.
// K:   kd[r,pos] = xn[pos] @ Wk[r], needed pos in [511-r, 512).
//      Stored at tri(pos) + (pos-(511-r)).
// v15 = v14 (async global_load_lds A dbuf, reg-resident B-frags) +
// (1) compiler cvt for f32->bf16 (VALU was the top busy counter at 29%),
// (2) counted-vmcnt barrier: s_waitcnt vmcnt(16) + raw s_barrier lets the
//     16 output stores fly across the tile boundary (only the 8 DMA loads,
//     issued first, must drain). T4: never vmcnt(0) in the steady loop.
__global__ void __launch_bounds__(256) proj_kernel(
        const u16* __restrict__ xn,
        const float* __restrict__ Wq, const float* __restrict__ Wk,
        const float* __restrict__ Wv,
        u16* __restrict__ Qa, u16* __restrict__ Ka, u16* __restrict__ Va) {
    __shared__ char lds[65536];
    char* buf0 = lds;            // Wl first, then odd tiles
    char* buf1 = lds + 32768;    // even tiles

    int bid = blockIdx.x;
    int which = bid >> 11;          // 0=Q,1=K,2=V (2048 blocks each)
    int rr = bid & 2047;
    int r  = (which == 1) ? (511 - (rr >> 2)) : (rr >> 2);  // heavy first
    int cs = rr & 3;
    const float* W = (which == 0) ? Wq : ((which == 1) ? Wk : Wv);
    u16* Out       = (which == 0) ? Qa : ((which == 1) ? Ka : Va);
    int rows  = (which == 1) ? (r + 1) : (512 - r);
    int pbase = (which == 1) ? (511 - r) : 0;   // xn position = pbase + ml
    int nbase = (which == 1) ? (511 - r) : r;   // attn row n = nbase + ml

    int t = threadIdx.x;
    int c0 = cs * 64;
    int wv  = t >> 6;               // 0..3
    int rg  = wv >> 1;              // row-group: rows [rg*32, rg*32+32)
    int cg  = wv & 1;               // col-group: cols [cg*32, cg*32+32)
    int L   = t & 63;
    int l15 = L & 15, l4 = L >> 4;

    // ---- async A-tile DMA: wave wv covers tile rows [wv*16, wv*16+16) ----
    // LDS linear; global source pre-swizzled: LDS[row][s] = xn[grow][s^(row&7)]
#define DMA_TILE(DST, M0) do {                                                \
    _Pragma("unroll")                                                         \
    for (int j = 0; j < 8; ++j) {                                             \
        int lrow = wv * 16 + 2 * j + (L >> 5);                                \
        int grow = pbase + (M0) + lrow; if (grow > 511) grow = 511;           \
        const char* gp = (const char*)xn + (size_t)grow * 512                 \
                         + (((L & 31) ^ (lrow & 7)) << 4);                    \
        char* lp = (DST) + (wv * 16 + 2 * j) * 512;                           \
        gload_lds16(gp, lp);                                                  \
    }                                                                         \
} while (0)

    DMA_TILE(buf1, 0);              // tile 0 flies under the W stage

    // ---- Wl stage into buf0: coalesced dwordx4 loads, pcol b64 writes ----
    {
        int c4 = (t & 15) * 4;      // 4 consecutive cols
        int kq = t >> 4;            // 0..15 -> k-quad base kq*4 (+64/IT)
        const float* wp = W + ((size_t)r << 16) + c0 + c4 + (size_t)(kq * 4) * 256;
        f32x4 w00 = *(const f32x4*)(wp + 0);
        f32x4 w01 = *(const f32x4*)(wp + 256);
        f32x4 w02 = *(const f32x4*)(wp + 512);
        f32x4 w03 = *(const f32x4*)(wp + 768);
        f32x4 w10 = *(const f32x4*)(wp + 16384 + 0);
        f32x4 w11 = *(const f32x4*)(wp + 16384 + 256);
        f32x4 w12 = *(const f32x4*)(wp + 16384 + 512);
        f32x4 w13 = *(const f32x4*)(wp + 16384 + 768);
        f32x4 w20 = *(const f32x4*)(wp + 32768 + 0);
        f32x4 w21 = *(const f32x4*)(wp + 32768 + 256);
        f32x4 w22 = *(const f32x4*)(wp + 32768 + 512);
        f32x4 w23 = *(const f32x4*)(wp + 32768 + 768);
        f32x4 w30 = *(const f32x4*)(wp + 49152 + 0);
        f32x4 w31 = *(const f32x4*)(wp + 49152 + 256);
        f32x4 w32 = *(const f32x4*)(wp + 49152 + 512);
        f32x4 w33 = *(const f32x4*)(wp + 49152 + 768);
#define WLW(IT, VA, VB, VC, VD) {                                             \
        int kbase2 = (kq * 4 + (IT) * 64) * 2;                                \
        _Pragma("unroll")                                                     \
        for (int i = 0; i < 4; ++i) {                                         \
            int col = c4 + i;                                                 \
            u32 lo = (u32)f2b(VA[i]) | ((u32)f2b(VB[i]) << 16);               \
            u32 hi = (u32)f2b(VC[i]) | ((u32)f2b(VD[i]) << 16);               \
            u32x2 pr; pr[0] = lo; pr[1] = hi;                                 \
            *(u32x2*)(buf0 + col * 512 + (kbase2 ^ pcol(col))) = pr;          \
        }                                                                     \
    }
        WLW(0, w00, w01, w02, w03)
        WLW(1, w10, w11, w12, w13)
        WLW(2, w20, w21, w22, w23)
        WLW(3, w30, w31, w32, w33)
#undef WLW
    }
    __syncthreads();                // Wl ready; tile-0 DMA drained

    // ---- B-frag extraction: 16 named bf16x8 from Wl ----
    bf16x8 b00, b01, b02, b03, b04, b05, b06, b07;
    bf16x8 b10, b11, b12, b13, b14, b15, b16, b17;
#define BEXT(HF, KSI, DST) {                                                  \
    int col = cg * 32 + (HF) * 16 + l15;                                      \
    int kb = (KSI) * 64 + l4 * 16;                                            \
    DST = *(const bf16x8*)(buf0 + col * 512 + (kb ^ pcol(col))); }
    BEXT(0, 0, b00) BEXT(0, 1, b01) BEXT(0, 2, b02) BEXT(0, 3, b03)
    BEXT(0, 4, b04) BEXT(0, 5, b05) BEXT(0, 6, b06) BEXT(0, 7, b07)
    BEXT(1, 0, b10) BEXT(1, 1, b11) BEXT(1, 2, b12) BEXT(1, 3, b13)
    BEXT(1, 4, b14) BEXT(1, 5, b15) BEXT(1, 6, b16) BEXT(1, 7, b17)
#undef BEXT
    __syncthreads();                // all extracts done; buf0 reusable as A

    int am = (l15 & 7) << 4;
    int nt = (rows + 63) >> 6;
    char* cur = buf1;
    char* alt = buf0;

    for (int i = 0; i < nt; ++i) {
        int m0 = i << 6;
        if (i + 1 < nt) DMA_TILE(alt, m0 + 64);   // 8 vmem, issued FIRST

        const char* abase = cur + (rg * 32 + l15) * 512;
        f32x4 acc00 = {}, acc01 = {}, acc10 = {}, acc11 = {};
#define KS(ks) {                                                              \
        int kb = (ks) * 64 + l4 * 16;                                         \
        bf16x8 a0 = *(const bf16x8*)(abase + (kb ^ am));                      \
        bf16x8 a1 = *(const bf16x8*)(abase + 16 * 512 + (kb ^ am));           \
        acc00 = __builtin_amdgcn_mfma_f32_16x16x32_bf16(a0, b0##ks, acc00, 0, 0, 0); \
        acc01 = __builtin_amdgcn_mfma_f32_16x16x32_bf16(a0, b1##ks, acc01, 0, 0, 0); \
        acc10 = __builtin_amdgcn_mfma_f32_16x16x32_bf16(a1, b0##ks, acc10, 0, 0, 0); \
        acc11 = __builtin_amdgcn_mfma_f32_16x16x32_bf16(a1, b1##ks, acc11, 0, 0, 0); \
    }
        KS(0) KS(1) KS(2) KS(3) KS(4) KS(5) KS(6) KS(7)
#undef KS

        // store to packed attention layout (16 vmem stores, issued AFTER DMA)
        #pragma unroll
        for (int rf = 0; rf < 2; ++rf) {
            #pragma unroll
            for (int j = 0; j < 4; ++j) {
                int ml = m0 + rg * 32 + rf * 16 + l4 * 4 + j;
                if (ml < rows) {
                    u32 nout = (u32)(nbase + ml);
                    u32 prow = (nout * (nout + 1)) >> 1;
                    u16* op = Out + (size_t)((u32)(prow + (u32)ml)) * 256
                              + c0 + cg * 32 + l15;
                    f32x4 va = rf ? acc10 : acc00;
                    f32x4 vb = rf ? acc11 : acc01;
                    op[0]  = f2b(va[j]);
                    op[16] = f2b(vb[j]);
                }
            }
        }
        // counted drain: wait only for own DMA (8 oldest); stores keep flying
        asm volatile("s_waitcnt vmcnt(16)" ::: "memory");
        __builtin_amdgcn_s_barrier();
        __builtin_amdgcn_sched_barrier(0);
        char* tmp = cur; cur = alt; alt = tmp;
    }
#undef DMA_TILE
}

// ---------------- per-row attention ----------------
// Block = one query row n. Band rows tri(n)..tri(n)+n hold per-pair q,k,v.
__global__ void __launch_bounds__(256) attn_kernel(const u16* __restrict__ Qa,
                                                   const u16* __restrict__ Ka,
                                                   const u16* __restrict__ Va,
                                                   float* __restrict__ ao) {
    int n = blockIdx.x, t = threadIdx.x;
    __shared__ float pbuf[512 * 9];   // [m][h] padded pitch 9
    __shared__ float linv[8];
    int band = n + 1;
    size_t rb = (size_t)(n * (n + 1) / 2);

    // scores: thread = (m-inner, h)
    int h = t & 7, mi = t >> 3;
    for (int m0 = 0; m0 < band; m0 += 32) {
        int m = m0 + mi;
        float d = -1e30f;
        if (m < band) {
            const char* qp = (const char*)Qa + (rb + m) * 512 + h * 64;
            const char* kp = (const char*)Ka + (rb + m) * 512 + h * 64;
            float acc = 0.f;
            #pragma unroll
            for (int cch = 0; cch < 4; ++cch) {
                u32x4 qv = *reinterpret_cast<const u32x4*>(qp + cch * 16);
                u32x4 kv = *reinterpret_cast<const u32x4*>(kp + cch * 16);
                #pragma unroll
                for (int i = 0; i < 4; ++i) {
                    float ql = __builtin_bit_cast(float, qv[i] << 16);
                    float qh = __builtin_bit_cast(float, qv[i] & 0xffff0000u);
                    float kl = __builtin_bit_cast(float, kv[i] << 16);
                    float kh = __builtin_bit_cast(float, kv[i] & 0xffff0000u);
                    acc += ql * kl + qh * kh;
                }
            }
            d = acc * 0.17677669529663687f;  // 1/sqrt(32)
        }
        pbuf[m * 9 + h] = d;
    }
    __syncthreads();

    // softmax per head: wave wv handles heads wv and wv+4
    int wv = t >> 6, L = t & 63;
    for (int s = 0; s < 2; ++s) {
        int hh = wv + s * 4;
        float mx = -1e30f;
        for (int m = L; m < band; m += 64) mx = fmaxf(mx, pbuf[m * 9 + hh]);
        #pragma unroll
        for (int o = 32; o >= 1; o >>= 1) mx = fmaxf(mx, __shfl_xor(mx, o));
        float sum = 0.f;
        for (int m = L; m < band; m += 64) {
            float p = __expf(pbuf[m * 9 + hh] - mx);
            pbuf[m * 9 + hh] = p;
            sum += p;
        }
        #pragma unroll
        for (int o = 32; o >= 1; o >>= 1) sum += __shfl_xor(sum, o);
        if (L == 0) linv[hh] = 1.0f / sum;
    }
    __syncthreads();

    // PV: thread = output channel t = h*32+e
    int h2 = t >> 5;
    const char* vp = (const char*)Va + rb * 512 + (size_t)t * 2;
    const float* pb = pbuf + h2;
    float a0 = 0, a1 = 0, a2 = 0, a3 = 0;
    int m = 0;
    for (; m + 4 <= band; m += 4) {
        a0 += pb[(m + 0) * 9] * b2f(*(const u16*)(vp + (size_t)(m + 0) * 512));
        a1 += pb[(m + 1) * 9] * b2f(*(const u16*)(vp + (size_t)(m + 1) * 512));
        a2 += pb[(m + 2) * 9] * b2f(*(const u16*)(vp + (size_t)(m + 2) * 512));
        a3 += pb[(m + 3) * 9] * b2f(*(const u16*)(vp + (size_t)(m + 3) * 512));
    }
    for (; m < band; ++m)
        a0 += pb[m * 9] * b2f(*(const u16*)(vp + (size_t)m * 512));
    ao[n * 256 + t] = ((a0 + a1) + (a2 + a3)) * linv[h2];
}

// ---------------- output projection ----------------
__global__ void __launch_bounds__(256) outproj_kernel(const float* __restrict__ ao,
                                                      const float* __restrict__ Wo,
                                                      const float* __restrict__ bo,
                                                      float* __restrict__ out) {
    int n = blockIdx.x, e = threadIdx.x;
    const float* a = ao + n * 256;
    float c0 = bo[e], c1 = 0, c2 = 0, c3 = 0;
    for (int c = 0; c < 256; c += 4) {
        c0 += a[c + 0] * Wo[(c + 0) * 256 + e];
        c1 += a[c + 1] * Wo[(c + 1) * 256 + e];
        c2 += a[c + 2] * Wo[(c + 2) * 256 + e];
        c3 += a[c + 3] * Wo[(c + 3) * 256 + e];
    }
    out[n * 256 + e] = (c0 + c1) + (c2 + c3);
}

extern "C" void kernel_launch(void* const* d_in, const int* in_sizes, int n_in,
                              void* d_out, int out_size, void* d_ws, size_t ws_size,
                              hipStream_t stream) {
    const float* x     = (const float*)d_in[0];
    const float* Wq    = (const float*)d_in[1];
    const float* Wk    = (const float*)d_in[2];
    const float* Wv    = (const float*)d_in[3];
    const float* gamma = (const float*)d_in[4];
    const float* beta  = (const float*)d_in[5];
    const float* Wo    = (const float*)d_in[6];
    const float* bo    = (const float*)d_in[7];
    float* out = (float*)d_out;

    char* ws = (char*)d_ws;
    u16* xn = (u16*)ws;
    size_t off = (size_t)512 * 256 * 2;
    u16* Qa = (u16*)(ws + off); off += (size_t)TRI_TOTAL * 256 * 2;
    u16* Ka = (u16*)(ws + off); off += (size_t)TRI_TOTAL * 256 * 2;
    u16* Va = (u16*)(ws + off); off += (size_t)TRI_TOTAL * 256 * 2;
    float* ao = (float*)(ws + off);

    ln_kernel<<<512, 256, 0, stream>>>(x, gamma, beta, xn);
    proj_kernel<<<6144, 256, 0, stream>>>(xn, Wq, Wk, Wv, Qa, Ka, Va);
    attn_kernel<<<512, 256, 0, stream>>>(Qa, Ka, Va, ao);
    outproj_kernel<<<512, 256, 0, stream>>>(ao, Wo, bo, out);
}